// Round 9
// baseline (494.392 us; speedup 1.0000x reference)
//
#include <hip/hip_runtime.h>
#include <cstdint>

#define NN 16384
#define FF 128
#define RR 16
#define HH 8
#define CC 64
#define HC 512
#define NC 1024          // fused Wl|Wr output width
#define EE 163840
#define ET (EE + NN)     // 180224 edges including self-loops (64-divisible)

typedef __attribute__((ext_vector_type(2))) float f32x2;
typedef __attribute__((ext_vector_type(4))) float f32x4;
typedef __attribute__((ext_vector_type(8))) short short8;

__device__ __forceinline__ unsigned short f2bf(float f) {
  unsigned u = __builtin_bit_cast(unsigned, f);
  u = (u + 0x7FFFu + ((u >> 16) & 1u)) >> 16;   // RNE
  return (unsigned short)u;
}
__device__ __forceinline__ float bf2f(unsigned short b) {
  unsigned u = ((unsigned)b) << 16;
  return __builtin_bit_cast(float, u);
}

__device__ __forceinline__ void gl_lds16(const void* g, void* l) {
  __builtin_amdgcn_global_load_lds(
      (const __attribute__((address_space(1))) unsigned int*)g,
      (__attribute__((address_space(3))) unsigned int*)l, 16, 0, 0);
}

// ---------------- CSR build (dst-sorted) ----------------
__global__ __launch_bounds__(256) void count_kernel(const int* __restrict__ ei,
                                                    int* __restrict__ counts) {
  int e = blockIdx.x * 256 + threadIdx.x;
  if (e >= ET) return;
  int d = (e < EE) ? ei[EE + e] : (e - EE);
  atomicAdd(&counts[d], 1);
}

__global__ __launch_bounds__(1024) void scan_kernel(const int* __restrict__ counts,
                                                    int* __restrict__ offs,
                                                    int* __restrict__ cursor) {
  __shared__ int part[1024];
  int t = threadIdx.x;
  int base = t * 16;
  int loc[16];
  int s = 0;
#pragma unroll
  for (int i = 0; i < 16; ++i) { loc[i] = s; s += counts[base + i]; }
  part[t] = s;
  __syncthreads();
  for (int off = 1; off < 1024; off <<= 1) {
    int v = (t >= off) ? part[t - off] : 0;
    __syncthreads();
    part[t] += v;
    __syncthreads();
  }
  int excl = part[t] - s;
#pragma unroll
  for (int i = 0; i < 16; ++i) {
    int o = excl + loc[i];
    offs[base + i] = o;
    cursor[base + i] = o;
  }
  if (t == 1023) offs[NN] = part[1023];
}

__global__ __launch_bounds__(256) void scatter_kernel(const int* __restrict__ ei,
                                                      int* __restrict__ cursor,
                                                      int* __restrict__ csr,
                                                      int* __restrict__ srcc) {
  int e = blockIdx.x * 256 + threadIdx.x;
  if (e >= ET) return;
  int s, d;
  if (e < EE) { s = ei[e]; d = ei[EE + e]; }
  else        { s = d = e - EE; }
  int p = atomicAdd(&cursor[d], 1);
  csr[p] = e;
  srcc[p] = s;
}

// ---------------- packing: fp32 -> split bf16 (hi/lo), k-chunk-tiled + swizzled ----------------
__global__ __launch_bounds__(256) void pack_a_kernel(const float* __restrict__ A,
                                                     unsigned short* __restrict__ Ah,
                                                     unsigned short* __restrict__ Al,
                                                     int K) {
  int nkb = K >> 5;
  int rb = blockIdx.x / nkb, kb = blockIdx.x % nkb;
  int t = threadIdx.x;
  size_t obase = ((size_t)rb * nkb + kb) * 4096;
#pragma unroll
  for (int u = 0; u < 2; ++u) {
    int lin = t + u * 256;          // r*4 + ch
    int r = lin >> 2, ch = lin & 3;
    int chs = (ch + (r >> 1)) & 3;
    const float* src = &A[(size_t)(rb * 128 + r) * K + kb * 32 + ch * 8];
    float4 v0 = *(const float4*)src;
    float4 v1 = *(const float4*)(src + 4);
    float v[8] = {v0.x, v0.y, v0.z, v0.w, v1.x, v1.y, v1.z, v1.w};
    short8 hv, lv;
#pragma unroll
    for (int j = 0; j < 8; ++j) {
      unsigned short h = f2bf(v[j]);
      unsigned short l = f2bf(v[j] - bf2f(h));
      hv[j] = (short)h; lv[j] = (short)l;
    }
    size_t o = obase + (size_t)r * 32 + chs * 8;
    *(short8*)&Ah[o] = hv;
    *(short8*)&Al[o] = lv;
  }
}

__global__ __launch_bounds__(256) void pack_w_kernel(const float* __restrict__ Wl,
                                                     const float* __restrict__ Wr,
                                                     unsigned short* __restrict__ Bh,
                                                     unsigned short* __restrict__ Bl,
                                                     int K) {
  int nkb = K >> 5;
  int nb = blockIdx.x / nkb, kb = blockIdx.x % nkb;
  int t = threadIdx.x;
  size_t obase = ((size_t)nb * nkb + kb) * 4096;
#pragma unroll
  for (int u = 0; u < 2; ++u) {
    int lin = t + u * 256;          // n*4 + ch
    int n = lin >> 2, ch = lin & 3;
    int chs = (ch + (n >> 1)) & 3;
    int gn = nb * 128 + n;
    const float* W = (gn < HC) ? Wl : Wr;
    int cn = gn & (HC - 1);
    short8 hv, lv;
#pragma unroll
    for (int j = 0; j < 8; ++j) {
      float f = W[(size_t)(kb * 32 + ch * 8 + j) * HC + cn];
      unsigned short h = f2bf(f);
      unsigned short l = f2bf(f - bf2f(h));
      hv[j] = (short)h; lv[j] = (short)l;
    }
    size_t o = obase + (size_t)n * 32 + chs * 8;
    *(short8*)&Bh[o] = hv;
    *(short8*)&Bl[o] = lv;
  }
}

// ---------------- transpose We -> WeT[512 cols][16 rows] fp32 ----------------
__global__ __launch_bounds__(256) void pack_wet_kernel(const float* __restrict__ We,
                                                       float* __restrict__ WeT) {
  int i = blockIdx.x * 256 + threadIdx.x;   // 8192 = 512*16; i = c*16 + r
  int c = i >> 4, r = i & 15;
  WeT[i] = We[r * HC + c];
}

// ---------------- split-bf16 MFMA GEMM: C[M x 1024] = A[M x K] @ [Wl|Wr] + [bl|br] ----------------
__global__ __launch_bounds__(256) void gemm_mfma_kernel(const unsigned short* __restrict__ Ah,
                                                        const unsigned short* __restrict__ Al,
                                                        const unsigned short* __restrict__ Bh,
                                                        const unsigned short* __restrict__ Bl,
                                                        const float* __restrict__ bl,
                                                        const float* __restrict__ br,
                                                        float* __restrict__ C, int K) {
  __shared__ unsigned short lAh[4096], lAl[4096], lBh[4096], lBl[4096];
  int tid = threadIdx.x;
  int wave = tid >> 6, lane = tid & 63;
  int l15 = lane & 15, quad = lane >> 4;
  int wm = wave >> 1, wn = wave & 1;
  int nb = blockIdx.x, rb = blockIdx.y;
  int nkb = K >> 5;

  const unsigned short* src = (wave == 0) ? Ah : (wave == 1) ? Al : (wave == 2) ? Bh : Bl;
  unsigned short* dst = (wave == 0) ? lAh : (wave == 1) ? lAl : (wave == 2) ? lBh : lBl;
  int blk = (wave < 2) ? rb : nb;
  size_t gstep = 4096;
  const unsigned short* gbase = src + ((size_t)blk * nkb) * gstep + lane * 8;

  f32x4 acc[4][4];
#pragma unroll
  for (int i = 0; i < 4; ++i)
#pragma unroll
    for (int j = 0; j < 4; ++j) acc[i][j] = (f32x4){0.f, 0.f, 0.f, 0.f};

  int offA[4], offB[4];
#pragma unroll
  for (int t = 0; t < 4; ++t) {
    int ra = wm * 64 + t * 16 + l15;
    offA[t] = ra * 32 + ((quad + (ra >> 1)) & 3) * 8;
    int rbn = wn * 64 + t * 16 + l15;
    offB[t] = rbn * 32 + ((quad + (rbn >> 1)) & 3) * 8;
  }

  for (int kb = 0; kb < nkb; ++kb) {
    const unsigned short* g = gbase + (size_t)kb * gstep;
#pragma unroll
    for (int i = 0; i < 8; ++i)
      gl_lds16(g + i * 512, dst + i * 512);
    __syncthreads();

    short8 ah[4], al_[4], bh[4], bl_[4];
#pragma unroll
    for (int t = 0; t < 4; ++t) {
      ah[t]  = *(const short8*)&lAh[offA[t]];
      al_[t] = *(const short8*)&lAl[offA[t]];
      bh[t]  = *(const short8*)&lBh[offB[t]];
      bl_[t] = *(const short8*)&lBl[offB[t]];
    }
#pragma unroll
    for (int tm = 0; tm < 4; ++tm)
#pragma unroll
      for (int tn = 0; tn < 4; ++tn) {
        acc[tm][tn] = __builtin_amdgcn_mfma_f32_16x16x32_bf16(ah[tm], bh[tn], acc[tm][tn], 0, 0, 0);
        acc[tm][tn] = __builtin_amdgcn_mfma_f32_16x16x32_bf16(ah[tm], bl_[tn], acc[tm][tn], 0, 0, 0);
        acc[tm][tn] = __builtin_amdgcn_mfma_f32_16x16x32_bf16(al_[tm], bh[tn], acc[tm][tn], 0, 0, 0);
      }
    __syncthreads();
  }

#pragma unroll
  for (int tm = 0; tm < 4; ++tm) {
    int row = rb * 128 + wm * 64 + tm * 16 + quad * 4;
#pragma unroll
    for (int tn = 0; tn < 4; ++tn) {
      int col = nb * 128 + wn * 64 + tn * 16 + l15;
      float bias = (col < HC) ? bl[col] : br[col - HC];
#pragma unroll
      for (int r = 0; r < 4; ++r)
        C[(size_t)(row + r) * NC + col] = acc[tm][tn][r] + bias;
    }
  }
}

// ================= R9: fused kernel = R7 structure + residency + ILP + LDS eattr =================
// R8 verdict: at default occupancy the allocator ALWAYS forces live set to ~32-36
// VGPR (sink/remat/scratch-spill); only waves_per_eu(4,4) held 52 (R5). R5's loss
// was the serial per-edge chain (load->logit->5 shfl->exp->update, ~500cy) exposed
// at 4 waves/EU. Fixes bundled here:
//  (1) waves_per_eu(4,4): wf0/wf1 (32 VGPR) stay resident -> no per-edge We reloads.
//  (2) 2-way edge ILP: two independent gathers + logit/shfl chains per iteration,
//      combined online update (nm = v_max3(m,p0,p1), one rescale for both edges).
//  (3) eattr staged in LDS (chunks of <=64 edges, online softmax resumes across
//      chunks): 8 global loads/edge/thread -> 4 ds_read_b128 broadcasts; csr/srcc
//      read once during staging instead of per edge.
// Verification: fused VGPR_Count ~52-72 (if 32 -> (4,4) betrayed, abandon residency).

__device__ __forceinline__ float edge_logit(const float* ser,
                                            const f32x2* wf0, const f32x2* wf1,
                                            float2 amv, f32x2 lv, f32x2 rv) {
  const f32x4* e4 = (const f32x4*)ser;
  f32x4 a = e4[0], b = e4[1], c = e4[2], d = e4[3];   // 4x ds_read_b128 (broadcast)
  f32x2 er[8];
  er[0] = (f32x2){a.x, a.y}; er[1] = (f32x2){a.z, a.w};
  er[2] = (f32x2){b.x, b.y}; er[3] = (f32x2){b.z, b.w};
  er[4] = (f32x2){c.x, c.y}; er[5] = (f32x2){c.z, c.w};
  er[6] = (f32x2){d.x, d.y}; er[7] = (f32x2){d.z, d.w};
  f32x2 q0 = (f32x2){0.f, 0.f};
  f32x2 q1 = (f32x2){0.f, 0.f};
#pragma unroll
  for (int j = 0; j < 8; ++j) {
    q0 = __builtin_elementwise_fma(er[j], wf0[j], q0);   // v_pk_fma_f32
    q1 = __builtin_elementwise_fma(er[j], wf1[j], q1);
  }
  float z0 = lv.x + rv.x + (q0.x + q0.y);
  float z1 = lv.y + rv.y + (q1.x + q1.y);
  z0 = fmaf(0.2f, fminf(z0, 0.f), fmaxf(z0, 0.f));
  z1 = fmaf(0.2f, fminf(z1, 0.f), fmaxf(z1, 0.f));
  float p = fmaf(z0, amv.x, z1 * amv.y);
  p += __shfl_xor(p, 1);
  p += __shfl_xor(p, 2);
  p += __shfl_xor(p, 4);
  p += __shfl_xor(p, 8);
  p += __shfl_xor(p, 16);     // head logit, uniform over 32-lane head group
  return p;
}

__device__ __forceinline__ void fused_edge_body(
    const int* __restrict__ csr, const int* __restrict__ srcc,
    const int* __restrict__ offs, const float* __restrict__ eattr,
    const float* __restrict__ WeT, const float* __restrict__ att,
    const float* __restrict__ xlr, int n, int t,
    float& out0, float& out1) {
  __shared__ float se[64][16];
  __shared__ int ssrc[64];
  int c0 = t * 2;
  int beg = offs[n], end = offs[n + 1];
  // per-thread We columns (resident under waves_per_eu(4,4) — R5 evidence)
  f32x2 wf0[8], wf1[8];
  {
    const f32x2* w0 = (const f32x2*)&WeT[(size_t)c0 * RR];
    const f32x2* w1 = (const f32x2*)&WeT[(size_t)(c0 + 1) * RR];
#pragma unroll
    for (int j = 0; j < 8; ++j) { wf0[j] = w0[j]; wf1[j] = w1[j]; }
  }
  float2 amv = *(const float2*)&att[c0];
  f32x2 rv = *(const f32x2*)&xlr[(size_t)n * NC + HC + c0];   // dst row: once per block
  float m = -1e30f, l = 0.f;
  f32x2 acc = (f32x2){0.f, 0.f};
  for (int cb = beg; cb < end; cb += 64) {
    int cnt = end - cb;
    if (cnt > 64) cnt = 64;
    if (cb > beg) __syncthreads();        // protect se reuse across chunks
    if (t < cnt) ssrc[t] = srcc[cb + t];
    for (int q = t; q < cnt * 4; q += 256) {
      int i = q >> 2, r4 = (q & 3) << 2;
      int e = csr[cb + i];
      float4 v;
      if (e < EE) v = *(const float4*)&eattr[(size_t)e * RR + r4];
      else        v = make_float4(0.5f, 0.5f, 0.5f, 0.5f);
      *(float4*)&se[i][r4] = v;
    }
    __syncthreads();
    int i = 0;
    for (; i + 2 <= cnt; i += 2) {
      int s0 = ssrc[i], s1 = ssrc[i + 1];
      f32x2 lv0 = *(const f32x2*)&xlr[(size_t)s0 * NC + c0];
      f32x2 lv1 = *(const f32x2*)&xlr[(size_t)s1 * NC + c0];
      float p0 = edge_logit(se[i],     wf0, wf1, amv, lv0, rv);
      float p1 = edge_logit(se[i + 1], wf0, wf1, amv, lv1, rv);
      float nm = fmaxf(fmaxf(m, p0), p1);          // v_max3_f32
      float sc = __expf(m - nm);
      float e0 = __expf(p0 - nm);
      float e1 = __expf(p1 - nm);
      l = l * sc + e0 + e1;
      acc.x = acc.x * sc + e0 * lv0.x + e1 * lv1.x;
      acc.y = acc.y * sc + e0 * lv0.y + e1 * lv1.y;
      m = nm;
    }
    if (i < cnt) {
      int s0 = ssrc[i];
      f32x2 lv0 = *(const f32x2*)&xlr[(size_t)s0 * NC + c0];
      float p0 = edge_logit(se[i], wf0, wf1, amv, lv0, rv);
      float nm = fmaxf(m, p0);
      float sc = __expf(m - nm);
      float e0 = __expf(p0 - nm);
      l = l * sc + e0;
      acc.x = acc.x * sc + e0 * lv0.x;
      acc.y = acc.y * sc + e0 * lv0.y;
      m = nm;
    }
  }
  float inv = 1.f / (l + 1e-16f);
  out0 = acc.x * inv;
  out1 = acc.y * inv;
}

// layer 1: +bias, emit packed split-bf16 A for layer-2 GEMM
__global__ __launch_bounds__(256)
__attribute__((amdgpu_waves_per_eu(4, 4)))
void fused_concat_kernel(
    const int* __restrict__ csr, const int* __restrict__ srcc,
    const int* __restrict__ offs, const float* __restrict__ eattr,
    const float* __restrict__ WeT, const float* __restrict__ att,
    const float* __restrict__ xlr, const float* __restrict__ bias,
    unsigned short* __restrict__ Ah2, unsigned short* __restrict__ Al2) {
  int n = blockIdx.x, t = threadIdx.x;
  float o0, o1;
  fused_edge_body(csr, srcc, offs, eattr, WeT, att, xlr, n, t, o0, o1);
  int c0 = t * 2;
  float v0 = o0 + bias[c0];
  float v1 = o1 + bias[c0 + 1];
  int r = n & 127, rbk = n >> 7;
#pragma unroll
  for (int u = 0; u < 2; ++u) {
    int c = c0 + u;
    float v = u ? v1 : v0;
    int kb = c >> 5, ch = (c >> 3) & 3, j = c & 7;
    int chs = (ch + (r >> 1)) & 3;
    size_t idx = ((size_t)rbk * 16 + kb) * 4096 + (size_t)r * 32 + chs * 8 + j;
    unsigned short h = f2bf(v);
    Ah2[idx] = h;
    Al2[idx] = f2bf(v - bf2f(h));
  }
}

// layer 2: mean over heads + bias2 -> out
__global__ __launch_bounds__(256)
__attribute__((amdgpu_waves_per_eu(4, 4)))
void fused_mean_kernel(
    const int* __restrict__ csr, const int* __restrict__ srcc,
    const int* __restrict__ offs, const float* __restrict__ eattr,
    const float* __restrict__ WeT, const float* __restrict__ att,
    const float* __restrict__ xlr, const float* __restrict__ bias2,
    float* __restrict__ out) {
  __shared__ float red[HC];
  int n = blockIdx.x, t = threadIdx.x;
  float o0, o1;
  fused_edge_body(csr, srcc, offs, eattr, WeT, att, xlr, n, t, o0, o1);
  int c0 = t * 2;
  red[c0] = o0;
  red[c0 + 1] = o1;
  __syncthreads();
  if (t < CC) {
    float ssum = 0.f;
#pragma unroll
    for (int hh = 0; hh < HH; ++hh) ssum += red[hh * CC + t];
    out[(size_t)n * CC + t] = ssum * 0.125f + bias2[t];
  }
}

extern "C" void kernel_launch(void* const* d_in, const int* in_sizes, int n_in,
                              void* d_out, int out_size, void* d_ws, size_t ws_size,
                              hipStream_t stream) {
  const float* x     = (const float*)d_in[0];
  const int*   ei    = (const int*)d_in[1];
  const float* eattr = (const float*)d_in[2];
  const float* Wl1   = (const float*)d_in[3];
  const float* bl1   = (const float*)d_in[4];
  const float* Wr1   = (const float*)d_in[5];
  const float* br1   = (const float*)d_in[6];
  const float* We1   = (const float*)d_in[7];
  const float* att1  = (const float*)d_in[8];
  const float* bias1 = (const float*)d_in[9];
  const float* Wl2   = (const float*)d_in[10];
  const float* bl2   = (const float*)d_in[11];
  const float* Wr2   = (const float*)d_in[12];
  const float* br2   = (const float*)d_in[13];
  const float* We2   = (const float*)d_in[14];
  const float* att2  = (const float*)d_in[15];
  const float* bias2 = (const float*)d_in[16];
  float* out = (float*)d_out;

  char* ws = (char*)d_ws;
  size_t off = 0;
  auto alloc = [&](size_t bytes) {
    char* p = ws + off;
    off += (bytes + 255) & ~(size_t)255;
    return p;
  };
  float* bufC = (float*)alloc((size_t)NN * NC * 4);            // fused xl|xr (both layers)
  unsigned short* Ah1 = (unsigned short*)alloc((size_t)NN * FF * 2);
  unsigned short* Al1 = (unsigned short*)alloc((size_t)NN * FF * 2);
  unsigned short* Ah2 = (unsigned short*)alloc((size_t)NN * HC * 2);
  unsigned short* Al2 = (unsigned short*)alloc((size_t)NN * HC * 2);
  unsigned short* Wh1 = (unsigned short*)alloc((size_t)FF * NC * 2);
  unsigned short* Wlo1 = (unsigned short*)alloc((size_t)FF * NC * 2);
  unsigned short* Wh2 = (unsigned short*)alloc((size_t)HC * NC * 2);
  unsigned short* Wlo2 = (unsigned short*)alloc((size_t)HC * NC * 2);
  float* WeT1 = (float*)alloc((size_t)HC * RR * 4);            // We1^T fp32 [512][16]
  float* WeT2 = (float*)alloc((size_t)HC * RR * 4);            // We2^T fp32 [512][16]
  int* counts = (int*)alloc((size_t)NN * 4);
  int* offs   = (int*)alloc((size_t)(NN + 1) * 4);
  int* cursor = (int*)alloc((size_t)NN * 4);
  int* csr    = (int*)alloc((size_t)ET * 4);
  int* srcc   = (int*)alloc((size_t)ET * 4);
  (void)ws_size; (void)in_sizes; (void)n_in; (void)out_size;

  // CSR build (every launch; ws is re-poisoned)
  hipMemsetAsync(counts, 0, (size_t)NN * 4, stream);
  int eb = (ET + 255) / 256;
  count_kernel<<<eb, 256, 0, stream>>>(ei, counts);
  scan_kernel<<<1, 1024, 0, stream>>>(counts, offs, cursor);
  scatter_kernel<<<eb, 256, 0, stream>>>(ei, cursor, csr, srcc);

  // pack operands
  pack_a_kernel<<<(NN / 128) * (FF / 32), 256, 0, stream>>>(x, Ah1, Al1, FF);
  pack_w_kernel<<<(NC / 128) * (FF / 32), 256, 0, stream>>>(Wl1, Wr1, Wh1, Wlo1, FF);
  pack_w_kernel<<<(NC / 128) * (HC / 32), 256, 0, stream>>>(Wl2, Wr2, Wh2, Wlo2, HC);
  pack_wet_kernel<<<(HC * RR) / 256, 256, 0, stream>>>(We1, WeT1);
  pack_wet_kernel<<<(HC * RR) / 256, 256, 0, stream>>>(We2, WeT2);

  dim3 ggrid(NC / 128, NN / 128);

  // ---- layer 1 ----
  gemm_mfma_kernel<<<ggrid, 256, 0, stream>>>(Ah1, Al1, Wh1, Wlo1, bl1, br1, bufC, FF);
  fused_concat_kernel<<<NN, 256, 0, stream>>>(csr, srcc, offs, eattr, WeT1, att1, bufC, bias1, Ah2, Al2);

  // ---- layer 2 ----
  gemm_mfma_kernel<<<ggrid, 256, 0, stream>>>(Ah2, Al2, Wh2, Wlo2, bl2, br2, bufC, HC);
  fused_mean_kernel<<<NN, 256, 0, stream>>>(csr, srcc, offs, eattr, WeT2, att2, bufC, bias2, out);
}

// Round 10
// 464.672 us; speedup vs baseline: 1.0640x; 1.0640x over previous
//
#include <hip/hip_runtime.h>
#include <cstdint>

#define NN 16384
#define FF 128
#define RR 16
#define HH 8
#define CC 64
#define HC 512
#define NC 1024          // fused Wl|Wr output width
#define EE 163840
#define ET (EE + NN)     // 180224 edges including self-loops (64-divisible)

typedef __attribute__((ext_vector_type(2))) float f32x2;
typedef __attribute__((ext_vector_type(4))) float f32x4;
typedef __attribute__((ext_vector_type(8))) short short8;

__device__ __forceinline__ unsigned short f2bf(float f) {
  unsigned u = __builtin_bit_cast(unsigned, f);
  u = (u + 0x7FFFu + ((u >> 16) & 1u)) >> 16;   // RNE
  return (unsigned short)u;
}
__device__ __forceinline__ float bf2f(unsigned short b) {
  unsigned u = ((unsigned)b) << 16;
  return __builtin_bit_cast(float, u);
}
__device__ __forceinline__ unsigned short f2h(float f) {
  return __builtin_bit_cast(unsigned short, (_Float16)f);
}
__device__ __forceinline__ float h2f(unsigned short h) {
  return (float)__builtin_bit_cast(_Float16, h);
}

__device__ __forceinline__ void gl_lds16(const void* g, void* l) {
  __builtin_amdgcn_global_load_lds(
      (const __attribute__((address_space(1))) unsigned int*)g,
      (__attribute__((address_space(3))) unsigned int*)l, 16, 0, 0);
}

// ---------------- CSR build (dst-sorted) ----------------
__global__ __launch_bounds__(256) void count_kernel(const int* __restrict__ ei,
                                                    int* __restrict__ counts) {
  int e = blockIdx.x * 256 + threadIdx.x;
  if (e >= ET) return;
  int d = (e < EE) ? ei[EE + e] : (e - EE);
  atomicAdd(&counts[d], 1);
}

__global__ __launch_bounds__(1024) void scan_kernel(const int* __restrict__ counts,
                                                    int* __restrict__ offs,
                                                    int* __restrict__ cursor) {
  __shared__ int part[1024];
  int t = threadIdx.x;
  int base = t * 16;
  int loc[16];
  int s = 0;
#pragma unroll
  for (int i = 0; i < 16; ++i) { loc[i] = s; s += counts[base + i]; }
  part[t] = s;
  __syncthreads();
  for (int off = 1; off < 1024; off <<= 1) {
    int v = (t >= off) ? part[t - off] : 0;
    __syncthreads();
    part[t] += v;
    __syncthreads();
  }
  int excl = part[t] - s;
#pragma unroll
  for (int i = 0; i < 16; ++i) {
    int o = excl + loc[i];
    offs[base + i] = o;
    cursor[base + i] = o;
  }
  if (t == 1023) offs[NN] = part[1023];
}

__global__ __launch_bounds__(256) void scatter_kernel(const int* __restrict__ ei,
                                                      int* __restrict__ cursor,
                                                      int* __restrict__ csr,
                                                      int* __restrict__ srcc) {
  int e = blockIdx.x * 256 + threadIdx.x;
  if (e >= ET) return;
  int s, d;
  if (e < EE) { s = ei[e]; d = ei[EE + e]; }
  else        { s = d = e - EE; }
  int p = atomicAdd(&cursor[d], 1);
  csr[p] = e;
  srcc[p] = s;
}

// ---------------- packing: fp32 -> split bf16 (hi/lo), k-chunk-tiled + swizzled ----------------
__global__ __launch_bounds__(256) void pack_a_kernel(const float* __restrict__ A,
                                                     unsigned short* __restrict__ Ah,
                                                     unsigned short* __restrict__ Al,
                                                     int K) {
  int nkb = K >> 5;
  int rb = blockIdx.x / nkb, kb = blockIdx.x % nkb;
  int t = threadIdx.x;
  size_t obase = ((size_t)rb * nkb + kb) * 4096;
#pragma unroll
  for (int u = 0; u < 2; ++u) {
    int lin = t + u * 256;          // r*4 + ch
    int r = lin >> 2, ch = lin & 3;
    int chs = (ch + (r >> 1)) & 3;
    const float* src = &A[(size_t)(rb * 128 + r) * K + kb * 32 + ch * 8];
    float4 v0 = *(const float4*)src;
    float4 v1 = *(const float4*)(src + 4);
    float v[8] = {v0.x, v0.y, v0.z, v0.w, v1.x, v1.y, v1.z, v1.w};
    short8 hv, lv;
#pragma unroll
    for (int j = 0; j < 8; ++j) {
      unsigned short h = f2bf(v[j]);
      unsigned short l = f2bf(v[j] - bf2f(h));
      hv[j] = (short)h; lv[j] = (short)l;
    }
    size_t o = obase + (size_t)r * 32 + chs * 8;
    *(short8*)&Ah[o] = hv;
    *(short8*)&Al[o] = lv;
  }
}

__global__ __launch_bounds__(256) void pack_w_kernel(const float* __restrict__ Wl,
                                                     const float* __restrict__ Wr,
                                                     unsigned short* __restrict__ Bh,
                                                     unsigned short* __restrict__ Bl,
                                                     int K) {
  int nkb = K >> 5;
  int nb = blockIdx.x / nkb, kb = blockIdx.x % nkb;
  int t = threadIdx.x;
  size_t obase = ((size_t)nb * nkb + kb) * 4096;
#pragma unroll
  for (int u = 0; u < 2; ++u) {
    int lin = t + u * 256;          // n*4 + ch
    int n = lin >> 2, ch = lin & 3;
    int chs = (ch + (n >> 1)) & 3;
    int gn = nb * 128 + n;
    const float* W = (gn < HC) ? Wl : Wr;
    int cn = gn & (HC - 1);
    short8 hv, lv;
#pragma unroll
    for (int j = 0; j < 8; ++j) {
      float f = W[(size_t)(kb * 32 + ch * 8 + j) * HC + cn];
      unsigned short h = f2bf(f);
      unsigned short l = f2bf(f - bf2f(h));
      hv[j] = (short)h; lv[j] = (short)l;
    }
    size_t o = obase + (size_t)n * 32 + chs * 8;
    *(short8*)&Bh[o] = hv;
    *(short8*)&Bl[o] = lv;
  }
}

// ---------------- transpose We -> WeT[512 cols][16 rows] fp32 ----------------
__global__ __launch_bounds__(256) void pack_wet_kernel(const float* __restrict__ We,
                                                       float* __restrict__ WeT) {
  int i = blockIdx.x * 256 + threadIdx.x;   // 8192 = 512*16; i = c*16 + r
  int c = i >> 4, r = i & 15;
  WeT[i] = We[r * HC + c];
}

// ---------------- split-bf16 MFMA GEMM: C[M x 1024] = A[M x K] @ [Wl|Wr] + [bl|br] ----------------
// R10: epilogue also emits fp16 side-copy of the xl half (cols < 512) -> xlh[N][512].
// The fused gather path reads xlh (4 B/thread/edge instead of 8 B) — halves the
// dominant random-gather traffic. fp16 (not bf16): rel err ~2^-11 keeps absmax near
// the current 4.88e-4. col<HC is uniform per block (nb<4), so the branch is free.
__global__ __launch_bounds__(256) void gemm_mfma_kernel(const unsigned short* __restrict__ Ah,
                                                        const unsigned short* __restrict__ Al,
                                                        const unsigned short* __restrict__ Bh,
                                                        const unsigned short* __restrict__ Bl,
                                                        const float* __restrict__ bl,
                                                        const float* __restrict__ br,
                                                        float* __restrict__ C,
                                                        unsigned short* __restrict__ Chh,
                                                        int K) {
  __shared__ unsigned short lAh[4096], lAl[4096], lBh[4096], lBl[4096];
  int tid = threadIdx.x;
  int wave = tid >> 6, lane = tid & 63;
  int l15 = lane & 15, quad = lane >> 4;
  int wm = wave >> 1, wn = wave & 1;
  int nb = blockIdx.x, rb = blockIdx.y;
  int nkb = K >> 5;

  const unsigned short* src = (wave == 0) ? Ah : (wave == 1) ? Al : (wave == 2) ? Bh : Bl;
  unsigned short* dst = (wave == 0) ? lAh : (wave == 1) ? lAl : (wave == 2) ? lBh : lBl;
  int blk = (wave < 2) ? rb : nb;
  size_t gstep = 4096;
  const unsigned short* gbase = src + ((size_t)blk * nkb) * gstep + lane * 8;

  f32x4 acc[4][4];
#pragma unroll
  for (int i = 0; i < 4; ++i)
#pragma unroll
    for (int j = 0; j < 4; ++j) acc[i][j] = (f32x4){0.f, 0.f, 0.f, 0.f};

  int offA[4], offB[4];
#pragma unroll
  for (int t = 0; t < 4; ++t) {
    int ra = wm * 64 + t * 16 + l15;
    offA[t] = ra * 32 + ((quad + (ra >> 1)) & 3) * 8;
    int rbn = wn * 64 + t * 16 + l15;
    offB[t] = rbn * 32 + ((quad + (rbn >> 1)) & 3) * 8;
  }

  for (int kb = 0; kb < nkb; ++kb) {
    const unsigned short* g = gbase + (size_t)kb * gstep;
#pragma unroll
    for (int i = 0; i < 8; ++i)
      gl_lds16(g + i * 512, dst + i * 512);
    __syncthreads();

    short8 ah[4], al_[4], bh[4], bl_[4];
#pragma unroll
    for (int t = 0; t < 4; ++t) {
      ah[t]  = *(const short8*)&lAh[offA[t]];
      al_[t] = *(const short8*)&lAl[offA[t]];
      bh[t]  = *(const short8*)&lBh[offB[t]];
      bl_[t] = *(const short8*)&lBl[offB[t]];
    }
#pragma unroll
    for (int tm = 0; tm < 4; ++tm)
#pragma unroll
      for (int tn = 0; tn < 4; ++tn) {
        acc[tm][tn] = __builtin_amdgcn_mfma_f32_16x16x32_bf16(ah[tm], bh[tn], acc[tm][tn], 0, 0, 0);
        acc[tm][tn] = __builtin_amdgcn_mfma_f32_16x16x32_bf16(ah[tm], bl_[tn], acc[tm][tn], 0, 0, 0);
        acc[tm][tn] = __builtin_amdgcn_mfma_f32_16x16x32_bf16(al_[tm], bh[tn], acc[tm][tn], 0, 0, 0);
      }
    __syncthreads();
  }

#pragma unroll
  for (int tm = 0; tm < 4; ++tm) {
    int row = rb * 128 + wm * 64 + tm * 16 + quad * 4;
#pragma unroll
    for (int tn = 0; tn < 4; ++tn) {
      int col = nb * 128 + wn * 64 + tn * 16 + l15;
      float bias = (col < HC) ? bl[col] : br[col - HC];
#pragma unroll
      for (int r = 0; r < 4; ++r) {
        float v = acc[tm][tn][r] + bias;
        C[(size_t)(row + r) * NC + col] = v;
        if (col < HC)                        // uniform: nb<4 -> xl half
          Chh[(size_t)(row + r) * HC + col] = f2h(v);
      }
    }
  }
}

// ================= R10: fused kernel = exact R7 structure + fp16 xl gathers =================
// R7-R9 verdict: occupancy/TLP dominates; keep R7's default-occupancy body (VGPR=32,
// occ ~70-80%), accept remat. This round halves gather BYTES instead of issues:
// lv read from fp16 xlh (4 B/thread/edge); eattr row via 4x f32x4 (was 8x f32x2).
// rv stays f32 from bufC (once per block).

__device__ __forceinline__ void fused_edge_body(
    const int* __restrict__ csr, const int* __restrict__ srcc,
    const int* __restrict__ offs, const float* __restrict__ eattr,
    const float* __restrict__ WeT, const float* __restrict__ att,
    const float* __restrict__ xlr, const unsigned short* __restrict__ xlh,
    int n, int t, float& out0, float& out1) {
  int c0 = t * 2;
  int beg = offs[n], end = offs[n + 1];
  // per-thread We columns (r-paired for v_pk_fma_f32)
  f32x2 wf0[8], wf1[8];
  {
    const f32x2* w0 = (const f32x2*)&WeT[(size_t)c0 * RR];
    const f32x2* w1 = (const f32x2*)&WeT[(size_t)(c0 + 1) * RR];
#pragma unroll
    for (int j = 0; j < 8; ++j) { wf0[j] = w0[j]; wf1[j] = w1[j]; }
  }
  float2 amv = *(const float2*)&att[c0];
  f32x2 rv = *(const f32x2*)&xlr[(size_t)n * NC + HC + c0];   // dst row: once per block
  float m = -1e30f, l = 0.f;
  f32x2 acc = (f32x2){0.f, 0.f};
#pragma unroll 2
  for (int i = beg; i < end; ++i) {
    int e = csr[i];                 // broadcast loads (uniform addr across wave)
    int s = srcc[i];
    // fp16 xl gather: 4 B/thread (was 8 B f32)
    unsigned lu = *(const unsigned*)&xlh[(size_t)s * HC + c0];
    f32x2 lv = (f32x2){h2f((unsigned short)(lu & 0xFFFFu)),
                       h2f((unsigned short)(lu >> 16))};
    // eattr row: 4x f32x4 (was 8x f32x2) — half the VMEM issues
    f32x4 ea0, ea1, ea2, ea3;
    if (e < EE) {
      const f32x4* ep4 = (const f32x4*)&eattr[(size_t)e * RR];
      ea0 = ep4[0]; ea1 = ep4[1]; ea2 = ep4[2]; ea3 = ep4[3];
    } else {
      ea0 = ea1 = ea2 = ea3 = (f32x4){0.5f, 0.5f, 0.5f, 0.5f};
    }
    f32x2 er[8];
    er[0] = __builtin_shufflevector(ea0, ea0, 0, 1);
    er[1] = __builtin_shufflevector(ea0, ea0, 2, 3);
    er[2] = __builtin_shufflevector(ea1, ea1, 0, 1);
    er[3] = __builtin_shufflevector(ea1, ea1, 2, 3);
    er[4] = __builtin_shufflevector(ea2, ea2, 0, 1);
    er[5] = __builtin_shufflevector(ea2, ea2, 2, 3);
    er[6] = __builtin_shufflevector(ea3, ea3, 0, 1);
    er[7] = __builtin_shufflevector(ea3, ea3, 2, 3);
    f32x2 epp0 = (f32x2){0.f, 0.f};
    f32x2 epp1 = (f32x2){0.f, 0.f};
#pragma unroll
    for (int j = 0; j < 8; ++j) {
      epp0 = __builtin_elementwise_fma(er[j], wf0[j], epp0);   // v_pk_fma_f32
      epp1 = __builtin_elementwise_fma(er[j], wf1[j], epp1);
    }
    f32x2 base2 = lv + rv;
    float z0 = base2.x + (epp0.x + epp0.y);
    float z1 = base2.y + (epp1.x + epp1.y);
    z0 = fmaf(0.2f, fminf(z0, 0.f), fmaxf(z0, 0.f));
    z1 = fmaf(0.2f, fminf(z1, 0.f), fmaxf(z1, 0.f));
    float p = fmaf(z0, amv.x, z1 * amv.y);
    p += __shfl_xor(p, 1);
    p += __shfl_xor(p, 2);
    p += __shfl_xor(p, 4);
    p += __shfl_xor(p, 8);
    p += __shfl_xor(p, 16);         // head logit, uniform over 32-lane head group
    float nm = fmaxf(m, p);
    float sc = __expf(m - nm);
    float el = __expf(p - nm);
    l = l * sc + el;
    acc.x = acc.x * sc + el * lv.x;
    acc.y = acc.y * sc + el * lv.y;
    m = nm;
  }
  float inv = 1.f / (l + 1e-16f);
  out0 = acc.x * inv;
  out1 = acc.y * inv;
}

// layer 1: +bias, emit packed split-bf16 A for layer-2 GEMM
__global__ __launch_bounds__(256) void fused_concat_kernel(
    const int* __restrict__ csr, const int* __restrict__ srcc,
    const int* __restrict__ offs, const float* __restrict__ eattr,
    const float* __restrict__ WeT, const float* __restrict__ att,
    const float* __restrict__ xlr, const unsigned short* __restrict__ xlh,
    const float* __restrict__ bias,
    unsigned short* __restrict__ Ah2, unsigned short* __restrict__ Al2) {
  int n = blockIdx.x, t = threadIdx.x;
  float o0, o1;
  fused_edge_body(csr, srcc, offs, eattr, WeT, att, xlr, xlh, n, t, o0, o1);
  int c0 = t * 2;
  float v0 = o0 + bias[c0];
  float v1 = o1 + bias[c0 + 1];
  int r = n & 127, rbk = n >> 7;
#pragma unroll
  for (int u = 0; u < 2; ++u) {
    int c = c0 + u;
    float v = u ? v1 : v0;
    int kb = c >> 5, ch = (c >> 3) & 3, j = c & 7;
    int chs = (ch + (r >> 1)) & 3;
    size_t idx = ((size_t)rbk * 16 + kb) * 4096 + (size_t)r * 32 + chs * 8 + j;
    unsigned short h = f2bf(v);
    Ah2[idx] = h;
    Al2[idx] = f2bf(v - bf2f(h));
  }
}

// layer 2: mean over heads + bias2 -> out
__global__ __launch_bounds__(256) void fused_mean_kernel(
    const int* __restrict__ csr, const int* __restrict__ srcc,
    const int* __restrict__ offs, const float* __restrict__ eattr,
    const float* __restrict__ WeT, const float* __restrict__ att,
    const float* __restrict__ xlr, const unsigned short* __restrict__ xlh,
    const float* __restrict__ bias2, float* __restrict__ out) {
  __shared__ float red[HC];
  int n = blockIdx.x, t = threadIdx.x;
  float o0, o1;
  fused_edge_body(csr, srcc, offs, eattr, WeT, att, xlr, xlh, n, t, o0, o1);
  int c0 = t * 2;
  red[c0] = o0;
  red[c0 + 1] = o1;
  __syncthreads();
  if (t < CC) {
    float ssum = 0.f;
#pragma unroll
    for (int hh = 0; hh < HH; ++hh) ssum += red[hh * CC + t];
    out[(size_t)n * CC + t] = ssum * 0.125f + bias2[t];
  }
}

extern "C" void kernel_launch(void* const* d_in, const int* in_sizes, int n_in,
                              void* d_out, int out_size, void* d_ws, size_t ws_size,
                              hipStream_t stream) {
  const float* x     = (const float*)d_in[0];
  const int*   ei    = (const int*)d_in[1];
  const float* eattr = (const float*)d_in[2];
  const float* Wl1   = (const float*)d_in[3];
  const float* bl1   = (const float*)d_in[4];
  const float* Wr1   = (const float*)d_in[5];
  const float* br1   = (const float*)d_in[6];
  const float* We1   = (const float*)d_in[7];
  const float* att1  = (const float*)d_in[8];
  const float* bias1 = (const float*)d_in[9];
  const float* Wl2   = (const float*)d_in[10];
  const float* bl2   = (const float*)d_in[11];
  const float* Wr2   = (const float*)d_in[12];
  const float* br2   = (const float*)d_in[13];
  const float* We2   = (const float*)d_in[14];
  const float* att2  = (const float*)d_in[15];
  const float* bias2 = (const float*)d_in[16];
  float* out = (float*)d_out;

  char* ws = (char*)d_ws;
  size_t off = 0;
  auto alloc = [&](size_t bytes) {
    char* p = ws + off;
    off += (bytes + 255) & ~(size_t)255;
    return p;
  };
  float* bufC = (float*)alloc((size_t)NN * NC * 4);            // fused xl|xr (both layers)
  unsigned short* xlh = (unsigned short*)alloc((size_t)NN * HC * 2);  // fp16 xl copy (gather path)
  unsigned short* Ah1 = (unsigned short*)alloc((size_t)NN * FF * 2);
  unsigned short* Al1 = (unsigned short*)alloc((size_t)NN * FF * 2);
  unsigned short* Ah2 = (unsigned short*)alloc((size_t)NN * HC * 2);
  unsigned short* Al2 = (unsigned short*)alloc((size_t)NN * HC * 2);
  unsigned short* Wh1 = (unsigned short*)alloc((size_t)FF * NC * 2);
  unsigned short* Wlo1 = (unsigned short*)alloc((size_t)FF * NC * 2);
  unsigned short* Wh2 = (unsigned short*)alloc((size_t)HC * NC * 2);
  unsigned short* Wlo2 = (unsigned short*)alloc((size_t)HC * NC * 2);
  float* WeT1 = (float*)alloc((size_t)HC * RR * 4);            // We1^T fp32 [512][16]
  float* WeT2 = (float*)alloc((size_t)HC * RR * 4);            // We2^T fp32 [512][16]
  int* counts = (int*)alloc((size_t)NN * 4);
  int* offs   = (int*)alloc((size_t)(NN + 1) * 4);
  int* cursor = (int*)alloc((size_t)NN * 4);
  int* csr    = (int*)alloc((size_t)ET * 4);
  int* srcc   = (int*)alloc((size_t)ET * 4);
  (void)ws_size; (void)in_sizes; (void)n_in; (void)out_size;

  // CSR build (every launch; ws is re-poisoned)
  hipMemsetAsync(counts, 0, (size_t)NN * 4, stream);
  int eb = (ET + 255) / 256;
  count_kernel<<<eb, 256, 0, stream>>>(ei, counts);
  scan_kernel<<<1, 1024, 0, stream>>>(counts, offs, cursor);
  scatter_kernel<<<eb, 256, 0, stream>>>(ei, cursor, csr, srcc);

  // pack operands
  pack_a_kernel<<<(NN / 128) * (FF / 32), 256, 0, stream>>>(x, Ah1, Al1, FF);
  pack_w_kernel<<<(NC / 128) * (FF / 32), 256, 0, stream>>>(Wl1, Wr1, Wh1, Wlo1, FF);
  pack_w_kernel<<<(NC / 128) * (HC / 32), 256, 0, stream>>>(Wl2, Wr2, Wh2, Wlo2, HC);
  pack_wet_kernel<<<(HC * RR) / 256, 256, 0, stream>>>(We1, WeT1);
  pack_wet_kernel<<<(HC * RR) / 256, 256, 0, stream>>>(We2, WeT2);

  dim3 ggrid(NC / 128, NN / 128);

  // ---- layer 1 ----
  gemm_mfma_kernel<<<ggrid, 256, 0, stream>>>(Ah1, Al1, Wh1, Wlo1, bl1, br1, bufC, xlh, FF);
  fused_concat_kernel<<<NN, 256, 0, stream>>>(csr, srcc, offs, eattr, WeT1, att1, bufC, xlh, bias1, Ah2, Al2);

  // ---- layer 2 ----
  gemm_mfma_kernel<<<ggrid, 256, 0, stream>>>(Ah2, Al2, Wh2, Wlo2, bl2, br2, bufC, xlh, HC);
  fused_mean_kernel<<<NN, 256, 0, stream>>>(csr, srcc, offs, eattr, WeT2, att2, bufC, xlh, bias2, out);
}

// Round 11
// 443.129 us; speedup vs baseline: 1.1157x; 1.0486x over previous
//
#include <hip/hip_runtime.h>
#include <cstdint>

#define NN 16384
#define FF 128
#define RR 16
#define HH 8
#define CC 64
#define HC 512
#define NC 1024          // fused Wl|Wr output width
#define EE 163840
#define ET (EE + NN)     // 180224 edges including self-loops (64-divisible)

typedef __attribute__((ext_vector_type(2))) float f32x2;
typedef __attribute__((ext_vector_type(4))) float f32x4;
typedef __attribute__((ext_vector_type(8))) short short8;

__device__ __forceinline__ unsigned short f2bf(float f) {
  unsigned u = __builtin_bit_cast(unsigned, f);
  u = (u + 0x7FFFu + ((u >> 16) & 1u)) >> 16;   // RNE
  return (unsigned short)u;
}
__device__ __forceinline__ float bf2f(unsigned short b) {
  unsigned u = ((unsigned)b) << 16;
  return __builtin_bit_cast(float, u);
}
__device__ __forceinline__ unsigned short f2h(float f) {
  return __builtin_bit_cast(unsigned short, (_Float16)f);
}
__device__ __forceinline__ float h2f(unsigned short h) {
  return (float)__builtin_bit_cast(_Float16, h);
}

__device__ __forceinline__ void gl_lds16(const void* g, void* l) {
  __builtin_amdgcn_global_load_lds(
      (const __attribute__((address_space(1))) unsigned int*)g,
      (__attribute__((address_space(3))) unsigned int*)l, 16, 0, 0);
}

// ---------------- CSR build (dst-sorted) ----------------
__global__ __launch_bounds__(256) void count_kernel(const int* __restrict__ ei,
                                                    int* __restrict__ counts) {
  int e = blockIdx.x * 256 + threadIdx.x;
  if (e >= ET) return;
  int d = (e < EE) ? ei[EE + e] : (e - EE);
  atomicAdd(&counts[d], 1);
}

__global__ __launch_bounds__(1024) void scan_kernel(const int* __restrict__ counts,
                                                    int* __restrict__ offs,
                                                    int* __restrict__ cursor) {
  __shared__ int part[1024];
  int t = threadIdx.x;
  int base = t * 16;
  int loc[16];
  int s = 0;
#pragma unroll
  for (int i = 0; i < 16; ++i) { loc[i] = s; s += counts[base + i]; }
  part[t] = s;
  __syncthreads();
  for (int off = 1; off < 1024; off <<= 1) {
    int v = (t >= off) ? part[t - off] : 0;
    __syncthreads();
    part[t] += v;
    __syncthreads();
  }
  int excl = part[t] - s;
#pragma unroll
  for (int i = 0; i < 16; ++i) {
    int o = excl + loc[i];
    offs[base + i] = o;
    cursor[base + i] = o;
  }
  if (t == 1023) offs[NN] = part[1023];
}

__global__ __launch_bounds__(256) void scatter_kernel(const int* __restrict__ ei,
                                                      int* __restrict__ cursor,
                                                      int* __restrict__ csr,
                                                      int* __restrict__ srcc) {
  int e = blockIdx.x * 256 + threadIdx.x;
  if (e >= ET) return;
  int s, d;
  if (e < EE) { s = ei[e]; d = ei[EE + e]; }
  else        { s = d = e - EE; }
  int p = atomicAdd(&cursor[d], 1);
  csr[p] = e;
  srcc[p] = s;
}

// ---------------- packing: fp32 -> split bf16 (hi/lo), k-chunk-tiled + swizzled ----------------
__global__ __launch_bounds__(256) void pack_a_kernel(const float* __restrict__ A,
                                                     unsigned short* __restrict__ Ah,
                                                     unsigned short* __restrict__ Al,
                                                     int K) {
  int nkb = K >> 5;
  int rb = blockIdx.x / nkb, kb = blockIdx.x % nkb;
  int t = threadIdx.x;
  size_t obase = ((size_t)rb * nkb + kb) * 4096;
#pragma unroll
  for (int u = 0; u < 2; ++u) {
    int lin = t + u * 256;          // r*4 + ch
    int r = lin >> 2, ch = lin & 3;
    int chs = (ch + (r >> 1)) & 3;
    const float* src = &A[(size_t)(rb * 128 + r) * K + kb * 32 + ch * 8];
    float4 v0 = *(const float4*)src;
    float4 v1 = *(const float4*)(src + 4);
    float v[8] = {v0.x, v0.y, v0.z, v0.w, v1.x, v1.y, v1.z, v1.w};
    short8 hv, lv;
#pragma unroll
    for (int j = 0; j < 8; ++j) {
      unsigned short h = f2bf(v[j]);
      unsigned short l = f2bf(v[j] - bf2f(h));
      hv[j] = (short)h; lv[j] = (short)l;
    }
    size_t o = obase + (size_t)r * 32 + chs * 8;
    *(short8*)&Ah[o] = hv;
    *(short8*)&Al[o] = lv;
  }
}

__global__ __launch_bounds__(256) void pack_w_kernel(const float* __restrict__ Wl,
                                                     const float* __restrict__ Wr,
                                                     unsigned short* __restrict__ Bh,
                                                     unsigned short* __restrict__ Bl,
                                                     int K) {
  int nkb = K >> 5;
  int nb = blockIdx.x / nkb, kb = blockIdx.x % nkb;
  int t = threadIdx.x;
  size_t obase = ((size_t)nb * nkb + kb) * 4096;
#pragma unroll
  for (int u = 0; u < 2; ++u) {
    int lin = t + u * 256;          // n*4 + ch
    int n = lin >> 2, ch = lin & 3;
    int chs = (ch + (n >> 1)) & 3;
    int gn = nb * 128 + n;
    const float* W = (gn < HC) ? Wl : Wr;
    int cn = gn & (HC - 1);
    short8 hv, lv;
#pragma unroll
    for (int j = 0; j < 8; ++j) {
      float f = W[(size_t)(kb * 32 + ch * 8 + j) * HC + cn];
      unsigned short h = f2bf(f);
      unsigned short l = f2bf(f - bf2f(h));
      hv[j] = (short)h; lv[j] = (short)l;
    }
    size_t o = obase + (size_t)n * 32 + chs * 8;
    *(short8*)&Bh[o] = hv;
    *(short8*)&Bl[o] = lv;
  }
}

// ---------------- transpose We -> WeT[512 cols][16 rows] fp32 ----------------
__global__ __launch_bounds__(256) void pack_wet_kernel(const float* __restrict__ We,
                                                       float* __restrict__ WeT) {
  int i = blockIdx.x * 256 + threadIdx.x;   // 8192 = 512*16; i = c*16 + r
  int c = i >> 4, r = i & 15;
  WeT[i] = We[r * HC + c];
}

// ---------------- split-bf16 MFMA GEMM: C[M x 1024] = A[M x K] @ [Wl|Wr] + [bl|br] ----------------
// R11: xl half (col<HC) stored ONLY as fp16 to Chh (the f32 copy was dead since R10
// — fused reads xlh; rv reads col>=HC). 64 stores/thread like R7 but 48 MB not 64.
__global__ __launch_bounds__(256) void gemm_mfma_kernel(const unsigned short* __restrict__ Ah,
                                                        const unsigned short* __restrict__ Al,
                                                        const unsigned short* __restrict__ Bh,
                                                        const unsigned short* __restrict__ Bl,
                                                        const float* __restrict__ bl,
                                                        const float* __restrict__ br,
                                                        float* __restrict__ C,
                                                        unsigned short* __restrict__ Chh,
                                                        int K) {
  __shared__ unsigned short lAh[4096], lAl[4096], lBh[4096], lBl[4096];
  int tid = threadIdx.x;
  int wave = tid >> 6, lane = tid & 63;
  int l15 = lane & 15, quad = lane >> 4;
  int wm = wave >> 1, wn = wave & 1;
  int nb = blockIdx.x, rb = blockIdx.y;
  int nkb = K >> 5;

  const unsigned short* src = (wave == 0) ? Ah : (wave == 1) ? Al : (wave == 2) ? Bh : Bl;
  unsigned short* dst = (wave == 0) ? lAh : (wave == 1) ? lAl : (wave == 2) ? lBh : lBl;
  int blk = (wave < 2) ? rb : nb;
  size_t gstep = 4096;
  const unsigned short* gbase = src + ((size_t)blk * nkb) * gstep + lane * 8;

  f32x4 acc[4][4];
#pragma unroll
  for (int i = 0; i < 4; ++i)
#pragma unroll
    for (int j = 0; j < 4; ++j) acc[i][j] = (f32x4){0.f, 0.f, 0.f, 0.f};

  int offA[4], offB[4];
#pragma unroll
  for (int t = 0; t < 4; ++t) {
    int ra = wm * 64 + t * 16 + l15;
    offA[t] = ra * 32 + ((quad + (ra >> 1)) & 3) * 8;
    int rbn = wn * 64 + t * 16 + l15;
    offB[t] = rbn * 32 + ((quad + (rbn >> 1)) & 3) * 8;
  }

  for (int kb = 0; kb < nkb; ++kb) {
    const unsigned short* g = gbase + (size_t)kb * gstep;
#pragma unroll
    for (int i = 0; i < 8; ++i)
      gl_lds16(g + i * 512, dst + i * 512);
    __syncthreads();

    short8 ah[4], al_[4], bh[4], bl_[4];
#pragma unroll
    for (int t = 0; t < 4; ++t) {
      ah[t]  = *(const short8*)&lAh[offA[t]];
      al_[t] = *(const short8*)&lAl[offA[t]];
      bh[t]  = *(const short8*)&lBh[offB[t]];
      bl_[t] = *(const short8*)&lBl[offB[t]];
    }
#pragma unroll
    for (int tm = 0; tm < 4; ++tm)
#pragma unroll
      for (int tn = 0; tn < 4; ++tn) {
        acc[tm][tn] = __builtin_amdgcn_mfma_f32_16x16x32_bf16(ah[tm], bh[tn], acc[tm][tn], 0, 0, 0);
        acc[tm][tn] = __builtin_amdgcn_mfma_f32_16x16x32_bf16(ah[tm], bl_[tn], acc[tm][tn], 0, 0, 0);
        acc[tm][tn] = __builtin_amdgcn_mfma_f32_16x16x32_bf16(al_[tm], bh[tn], acc[tm][tn], 0, 0, 0);
      }
    __syncthreads();
  }

#pragma unroll
  for (int tm = 0; tm < 4; ++tm) {
    int row = rb * 128 + wm * 64 + tm * 16 + quad * 4;
#pragma unroll
    for (int tn = 0; tn < 4; ++tn) {
      int col = nb * 128 + wn * 64 + tn * 16 + l15;
      bool xlh_half = (col < HC);            // uniform per block (nb<4)
      float bias = xlh_half ? bl[col] : br[col - HC];
#pragma unroll
      for (int r = 0; r < 4; ++r) {
        float v = acc[tm][tn][r] + bias;
        if (xlh_half)
          Chh[(size_t)(row + r) * HC + col] = f2h(v);
        else
          C[(size_t)(row + r) * NC + col] = v;
      }
    }
  }
}

// ================= R11: fused kernel = R10 + explicit 2-edge ILP =================
// R10 verdict: VALU-issue ~70us (unchanged from R7) is the floor; remaining stall
// is the serial per-edge chain (lv load -> logit -> 5 shfl -> exp -> update) that
// the compiler can't break (FP non-associativity). R11 processes 2 edges per
// iteration: independent gathers + two interleaved logit/shfl chains, then ONE
// combined online update (nm = max3(m,p0,p1), single rescale for both). Halves
// the chain at the default occupancy (78%) that R9's cap threw away.

__device__ __forceinline__ float edge_logit_g(
    int e, const float* __restrict__ eattr,
    const f32x2* wf0, const f32x2* wf1,
    float2 amv, f32x2 lv, f32x2 rv) {
  f32x4 ea0, ea1, ea2, ea3;
  if (e < EE) {
    const f32x4* ep4 = (const f32x4*)&eattr[(size_t)e * RR];
    ea0 = ep4[0]; ea1 = ep4[1]; ea2 = ep4[2]; ea3 = ep4[3];
  } else {
    ea0 = ea1 = ea2 = ea3 = (f32x4){0.5f, 0.5f, 0.5f, 0.5f};
  }
  f32x2 er[8];
  er[0] = __builtin_shufflevector(ea0, ea0, 0, 1);
  er[1] = __builtin_shufflevector(ea0, ea0, 2, 3);
  er[2] = __builtin_shufflevector(ea1, ea1, 0, 1);
  er[3] = __builtin_shufflevector(ea1, ea1, 2, 3);
  er[4] = __builtin_shufflevector(ea2, ea2, 0, 1);
  er[5] = __builtin_shufflevector(ea2, ea2, 2, 3);
  er[6] = __builtin_shufflevector(ea3, ea3, 0, 1);
  er[7] = __builtin_shufflevector(ea3, ea3, 2, 3);
  f32x2 epp0 = (f32x2){0.f, 0.f};
  f32x2 epp1 = (f32x2){0.f, 0.f};
#pragma unroll
  for (int j = 0; j < 8; ++j) {
    epp0 = __builtin_elementwise_fma(er[j], wf0[j], epp0);   // v_pk_fma_f32
    epp1 = __builtin_elementwise_fma(er[j], wf1[j], epp1);
  }
  float z0 = lv.x + rv.x + (epp0.x + epp0.y);
  float z1 = lv.y + rv.y + (epp1.x + epp1.y);
  z0 = fmaf(0.2f, fminf(z0, 0.f), fmaxf(z0, 0.f));
  z1 = fmaf(0.2f, fminf(z1, 0.f), fmaxf(z1, 0.f));
  float p = fmaf(z0, amv.x, z1 * amv.y);
  p += __shfl_xor(p, 1);
  p += __shfl_xor(p, 2);
  p += __shfl_xor(p, 4);
  p += __shfl_xor(p, 8);
  p += __shfl_xor(p, 16);     // head logit, uniform over 32-lane head group
  return p;
}

__device__ __forceinline__ f32x2 ld_xlh(const unsigned short* __restrict__ xlh,
                                        int s, int c0) {
  unsigned lu = *(const unsigned*)&xlh[(size_t)s * HC + c0];
  return (f32x2){h2f((unsigned short)(lu & 0xFFFFu)),
                 h2f((unsigned short)(lu >> 16))};
}

__device__ __forceinline__ void fused_edge_body(
    const int* __restrict__ csr, const int* __restrict__ srcc,
    const int* __restrict__ offs, const float* __restrict__ eattr,
    const float* __restrict__ WeT, const float* __restrict__ att,
    const float* __restrict__ xlr, const unsigned short* __restrict__ xlh,
    int n, int t, float& out0, float& out1) {
  int c0 = t * 2;
  int beg = offs[n], end = offs[n + 1];
  // per-thread We columns (r-paired for v_pk_fma_f32)
  f32x2 wf0[8], wf1[8];
  {
    const f32x2* w0 = (const f32x2*)&WeT[(size_t)c0 * RR];
    const f32x2* w1 = (const f32x2*)&WeT[(size_t)(c0 + 1) * RR];
#pragma unroll
    for (int j = 0; j < 8; ++j) { wf0[j] = w0[j]; wf1[j] = w1[j]; }
  }
  float2 amv = *(const float2*)&att[c0];
  f32x2 rv = *(const f32x2*)&xlr[(size_t)n * NC + HC + c0];   // dst row: once per block
  float m = -1e30f, l = 0.f;
  f32x2 acc = (f32x2){0.f, 0.f};
  int i = beg;
  for (; i + 2 <= end; i += 2) {
    int e0 = csr[i],     s0 = srcc[i];
    int e1 = csr[i + 1], s1 = srcc[i + 1];
    f32x2 lv0 = ld_xlh(xlh, s0, c0);
    f32x2 lv1 = ld_xlh(xlh, s1, c0);
    float p0 = edge_logit_g(e0, eattr, wf0, wf1, amv, lv0, rv);
    float p1 = edge_logit_g(e1, eattr, wf0, wf1, amv, lv1, rv);
    float nm = fmaxf(fmaxf(m, p0), p1);      // v_max3_f32
    float sc  = __expf(m - nm);
    float el0 = __expf(p0 - nm);
    float el1 = __expf(p1 - nm);
    l = l * sc + el0 + el1;
    acc.x = acc.x * sc + el0 * lv0.x + el1 * lv1.x;
    acc.y = acc.y * sc + el0 * lv0.y + el1 * lv1.y;
    m = nm;
  }
  if (i < end) {
    int e0 = csr[i], s0 = srcc[i];
    f32x2 lv0 = ld_xlh(xlh, s0, c0);
    float p0 = edge_logit_g(e0, eattr, wf0, wf1, amv, lv0, rv);
    float nm = fmaxf(m, p0);
    float sc  = __expf(m - nm);
    float el0 = __expf(p0 - nm);
    l = l * sc + el0;
    acc.x = acc.x * sc + el0 * lv0.x;
    acc.y = acc.y * sc + el0 * lv0.y;
    m = nm;
  }
  float inv = 1.f / (l + 1e-16f);
  out0 = acc.x * inv;
  out1 = acc.y * inv;
}

// layer 1: +bias, emit packed split-bf16 A for layer-2 GEMM
__global__ __launch_bounds__(256) void fused_concat_kernel(
    const int* __restrict__ csr, const int* __restrict__ srcc,
    const int* __restrict__ offs, const float* __restrict__ eattr,
    const float* __restrict__ WeT, const float* __restrict__ att,
    const float* __restrict__ xlr, const unsigned short* __restrict__ xlh,
    const float* __restrict__ bias,
    unsigned short* __restrict__ Ah2, unsigned short* __restrict__ Al2) {
  int n = blockIdx.x, t = threadIdx.x;
  float o0, o1;
  fused_edge_body(csr, srcc, offs, eattr, WeT, att, xlr, xlh, n, t, o0, o1);
  int c0 = t * 2;
  float v0 = o0 + bias[c0];
  float v1 = o1 + bias[c0 + 1];
  int r = n & 127, rbk = n >> 7;
#pragma unroll
  for (int u = 0; u < 2; ++u) {
    int c = c0 + u;
    float v = u ? v1 : v0;
    int kb = c >> 5, ch = (c >> 3) & 3, j = c & 7;
    int chs = (ch + (r >> 1)) & 3;
    size_t idx = ((size_t)rbk * 16 + kb) * 4096 + (size_t)r * 32 + chs * 8 + j;
    unsigned short h = f2bf(v);
    Ah2[idx] = h;
    Al2[idx] = f2bf(v - bf2f(h));
  }
}

// layer 2: mean over heads + bias2 -> out
__global__ __launch_bounds__(256) void fused_mean_kernel(
    const int* __restrict__ csr, const int* __restrict__ srcc,
    const int* __restrict__ offs, const float* __restrict__ eattr,
    const float* __restrict__ WeT, const float* __restrict__ att,
    const float* __restrict__ xlr, const unsigned short* __restrict__ xlh,
    const float* __restrict__ bias2, float* __restrict__ out) {
  __shared__ float red[HC];
  int n = blockIdx.x, t = threadIdx.x;
  float o0, o1;
  fused_edge_body(csr, srcc, offs, eattr, WeT, att, xlr, xlh, n, t, o0, o1);
  int c0 = t * 2;
  red[c0] = o0;
  red[c0 + 1] = o1;
  __syncthreads();
  if (t < CC) {
    float ssum = 0.f;
#pragma unroll
    for (int hh = 0; hh < HH; ++hh) ssum += red[hh * CC + t];
    out[(size_t)n * CC + t] = ssum * 0.125f + bias2[t];
  }
}

extern "C" void kernel_launch(void* const* d_in, const int* in_sizes, int n_in,
                              void* d_out, int out_size, void* d_ws, size_t ws_size,
                              hipStream_t stream) {
  const float* x     = (const float*)d_in[0];
  const int*   ei    = (const int*)d_in[1];
  const float* eattr = (const float*)d_in[2];
  const float* Wl1   = (const float*)d_in[3];
  const float* bl1   = (const float*)d_in[4];
  const float* Wr1   = (const float*)d_in[5];
  const float* br1   = (const float*)d_in[6];
  const float* We1   = (const float*)d_in[7];
  const float* att1  = (const float*)d_in[8];
  const float* bias1 = (const float*)d_in[9];
  const float* Wl2   = (const float*)d_in[10];
  const float* bl2   = (const float*)d_in[11];
  const float* Wr2   = (const float*)d_in[12];
  const float* br2   = (const float*)d_in[13];
  const float* We2   = (const float*)d_in[14];
  const float* att2  = (const float*)d_in[15];
  const float* bias2 = (const float*)d_in[16];
  float* out = (float*)d_out;

  char* ws = (char*)d_ws;
  size_t off = 0;
  auto alloc = [&](size_t bytes) {
    char* p = ws + off;
    off += (bytes + 255) & ~(size_t)255;
    return p;
  };
  float* bufC = (float*)alloc((size_t)NN * NC * 4);            // fused xl|xr (both layers)
  unsigned short* xlh = (unsigned short*)alloc((size_t)NN * HC * 2);  // fp16 xl copy (gather path)
  unsigned short* Ah1 = (unsigned short*)alloc((size_t)NN * FF * 2);
  unsigned short* Al1 = (unsigned short*)alloc((size_t)NN * FF * 2);
  unsigned short* Ah2 = (unsigned short*)alloc((size_t)NN * HC * 2);
  unsigned short* Al2 = (unsigned short*)alloc((size_t)NN * HC * 2);
  unsigned short* Wh1 = (unsigned short*)alloc((size_t)FF * NC * 2);
  unsigned short* Wlo1 = (unsigned short*)alloc((size_t)FF * NC * 2);
  unsigned short* Wh2 = (unsigned short*)alloc((size_t)HC * NC * 2);
  unsigned short* Wlo2 = (unsigned short*)alloc((size_t)HC * NC * 2);
  float* WeT1 = (float*)alloc((size_t)HC * RR * 4);            // We1^T fp32 [512][16]
  float* WeT2 = (float*)alloc((size_t)HC * RR * 4);            // We2^T fp32 [512][16]
  int* counts = (int*)alloc((size_t)NN * 4);
  int* offs   = (int*)alloc((size_t)(NN + 1) * 4);
  int* cursor = (int*)alloc((size_t)NN * 4);
  int* csr    = (int*)alloc((size_t)ET * 4);
  int* srcc   = (int*)alloc((size_t)ET * 4);
  (void)ws_size; (void)in_sizes; (void)n_in; (void)out_size;

  // CSR build (every launch; ws is re-poisoned)
  hipMemsetAsync(counts, 0, (size_t)NN * 4, stream);
  int eb = (ET + 255) / 256;
  count_kernel<<<eb, 256, 0, stream>>>(ei, counts);
  scan_kernel<<<1, 1024, 0, stream>>>(counts, offs, cursor);
  scatter_kernel<<<eb, 256, 0, stream>>>(ei, cursor, csr, srcc);

  // pack operands
  pack_a_kernel<<<(NN / 128) * (FF / 32), 256, 0, stream>>>(x, Ah1, Al1, FF);
  pack_w_kernel<<<(NC / 128) * (FF / 32), 256, 0, stream>>>(Wl1, Wr1, Wh1, Wlo1, FF);
  pack_w_kernel<<<(NC / 128) * (HC / 32), 256, 0, stream>>>(Wl2, Wr2, Wh2, Wlo2, HC);
  pack_wet_kernel<<<(HC * RR) / 256, 256, 0, stream>>>(We1, WeT1);
  pack_wet_kernel<<<(HC * RR) / 256, 256, 0, stream>>>(We2, WeT2);

  dim3 ggrid(NC / 128, NN / 128);

  // ---- layer 1 ----
  gemm_mfma_kernel<<<ggrid, 256, 0, stream>>>(Ah1, Al1, Wh1, Wlo1, bl1, br1, bufC, xlh, FF);
  fused_concat_kernel<<<NN, 256, 0, stream>>>(csr, srcc, offs, eattr, WeT1, att1, bufC, xlh, bias1, Ah2, Al2);

  // ---- layer 2 ----
  gemm_mfma_kernel<<<ggrid, 256, 0, stream>>>(Ah2, Al2, Wh2, Wlo2, bl2, br2, bufC, xlh, HC);
  fused_mean_kernel<<<NN, 256, 0, stream>>>(csr, srcc, offs, eattr, WeT2, att2, bufC, xlh, bias2, out);
}